// Round 7
// baseline (252.764 us; speedup 1.0000x reference)
//
#include <hip/hip_runtime.h>
#include <hip/hip_bf16.h>
#include <stdint.h>

#define E_EDGES 100000
#define IN_F    256
#define HID     128
#define KNB     16
#define NCHUNK  ((E_EDGES + 63) / 64)   // 1563
#define GEMM_GRID 512

// ---- sliced gather parameters ----
// NS=16 slices of 6250 rows = 1.6 MB bf16 each: the size r1/r4 both measured
// at 92-93 MB FETCH (two drifted slices still fit one 4 MiB per-XCD L2).
// r6's NS=8 (3.2 MB) measured 177 MB -> too big under drift.
#define NS          16
#define SLICE_ROWS  6250
#define GCHUNKS     5                    // 5 chunks x 16 edges = 80 edges/block
#define EDGES_PER_BLK (GCHUNKS * 16)     // 80
#define GATHER_GRID (E_EDGES / EDGES_PER_BLK)   // 1250, exact; 4 blocks/CU co-resident

typedef short bf16x8 __attribute__((ext_vector_type(8)));
typedef float f32x4  __attribute__((ext_vector_type(4)));

__device__ __forceinline__ unsigned short f2bf(float f) {
    union { float f; unsigned u; } v; v.f = f;
    unsigned u = v.u;
    u += 0x7fffu + ((u >> 16) & 1u);   // round-to-nearest-even
    return (unsigned short)(u >> 16);
}

// W [256][128] fp32 -> Wtf: bf16 in MFMA B-fragment order. (unchanged)
__global__ void conv_w_kernel(const float* __restrict__ W, unsigned short* __restrict__ Wtf) {
    int d = blockIdx.x * 256 + threadIdx.x;   // 0..4095
    int f = d >> 6, L = d & 63;
    int k0 = f >> 3, ct = f & 7, quad = L >> 4, l15 = L & 15;
    int n  = ct * 16 + l15;
    int kb = (k0 * 4 + quad) * 8;
    const float* wp = W + (size_t)kb * HID + n;
    unsigned short h[8];
    #pragma unroll
    for (int j = 0; j < 8; ++j) h[j] = f2bf(wp[(size_t)j * HID]);
    uint4 o;
    o.x = (unsigned)h[0] | ((unsigned)h[1] << 16);
    o.y = (unsigned)h[2] | ((unsigned)h[3] << 16);
    o.z = (unsigned)h[4] | ((unsigned)h[5] << 16);
    o.w = (unsigned)h[6] | ((unsigned)h[7] << 16);
    *(uint4*)(Wtf + (size_t)d * 8) = o;
}

// T = A @ W + b (A fp32, converted in-reg), stored bf16 [E][128]. (unchanged)
__launch_bounds__(256, 2)
__global__ void gemm_t_kernel(const float* __restrict__ A,
                              const unsigned short* __restrict__ Wtf,
                              const float* __restrict__ bias,
                              unsigned short* __restrict__ T) {
    __shared__ unsigned short Bs[32768];   // 64 KB, fragment order
    const int tid  = threadIdx.x;
    const int wave = tid >> 6;
    const int lane = tid & 63;
    const int l15  = lane & 15;
    const int quad = lane >> 4;

    int c = blockIdx.x;
    int arow = c * 64 + wave * 16 + l15;
    if (arow >= E_EDGES) arow = E_EDGES - 1;
    const float* ap = A + (size_t)arow * IN_F + quad * 8;
    float4 af32[16];
    #pragma unroll
    for (int k0 = 0; k0 < 8; ++k0) {
        af32[2 * k0]     = *(const float4*)(ap + k0 * 32);
        af32[2 * k0 + 1] = *(const float4*)(ap + k0 * 32 + 4);
    }

    #pragma unroll
    for (int it = 0; it < 16; ++it) {
        int d = it * 256 + tid;
        *(uint4*)(Bs + (size_t)d * 8) = *(const uint4*)(Wtf + (size_t)d * 8);
    }

    float4 bv4[8];
    #pragma unroll
    for (int ct = 0; ct < 8; ++ct)
        bv4[ct] = *(const float4*)(bias + ct * 16 + quad * 4);

    __syncthreads();

    for (; c < NCHUNK; c += GEMM_GRID) {
        bf16x8 apre[8];
        #pragma unroll
        for (int k0 = 0; k0 < 8; ++k0) {
            float4 lo = af32[2 * k0], hi = af32[2 * k0 + 1];
            bf16x8 f;
            f[0] = (short)f2bf(lo.x); f[1] = (short)f2bf(lo.y);
            f[2] = (short)f2bf(lo.z); f[3] = (short)f2bf(lo.w);
            f[4] = (short)f2bf(hi.x); f[5] = (short)f2bf(hi.y);
            f[6] = (short)f2bf(hi.z); f[7] = (short)f2bf(hi.w);
            apre[k0] = f;
        }

        {
            int cn = c + GEMM_GRID;
            int arow2 = cn * 64 + wave * 16 + l15;
            if (arow2 >= E_EDGES) arow2 = E_EDGES - 1;
            const float* ap2 = A + (size_t)arow2 * IN_F + quad * 8;
            #pragma unroll
            for (int k0 = 0; k0 < 8; ++k0) {
                af32[2 * k0]     = *(const float4*)(ap2 + k0 * 32);
                af32[2 * k0 + 1] = *(const float4*)(ap2 + k0 * 32 + 4);
            }
        }
        __builtin_amdgcn_sched_barrier(0);

        f32x4 acc[8] = {};
        #pragma unroll
        for (int k0 = 0; k0 < 8; ++k0) {
            #pragma unroll
            for (int ct = 0; ct < 8; ++ct) {
                bf16x8 bf = *(const bf16x8*)(Bs + ((size_t)((k0 * 8 + ct) * 64 + lane)) * 8);
                acc[ct] = __builtin_amdgcn_mfma_f32_16x16x32_bf16(bf, apre[k0], acc[ct], 0, 0, 0);
            }
        }

        const int row = c * 64 + wave * 16 + l15;
        if (row < E_EDGES) {
            unsigned short* tp = T + (size_t)row * HID + quad * 4;
            #pragma unroll
            for (int ct = 0; ct < 8; ++ct) {
                unsigned short h0 = f2bf(acc[ct][0] + bv4[ct].x);
                unsigned short h1 = f2bf(acc[ct][1] + bv4[ct].y);
                unsigned short h2 = f2bf(acc[ct][2] + bv4[ct].z);
                unsigned short h3 = f2bf(acc[ct][3] + bv4[ct].w);
                uint2 o;
                o.x = (unsigned)h0 | ((unsigned)h1 << 16);
                o.y = (unsigned)h2 | ((unsigned)h3 << 16);
                *(uint2*)(tp + ct * 16) = o;
            }
        }
    }
}

// bf16x8 (as uint4) -> two f32x4, BY VALUE (SROA-safe).
__device__ __forceinline__ float u2f(unsigned u) {
    union { unsigned u; float f; } c; c.u = u; return c.f;
}
__device__ __forceinline__ f32x4 declo(uint4 v) {
    f32x4 r = { u2f(v.x << 16), u2f(v.x & 0xffff0000u),
                u2f(v.y << 16), u2f(v.y & 0xffff0000u) };
    return r;
}
__device__ __forceinline__ f32x4 dechi(uint4 v) {
    f32x4 r = { u2f(v.z << 16), u2f(v.z & 0xffff0000u),
                u2f(v.w << 16), u2f(v.w & 0xffff0000u) };
    return r;
}

// out[i] = t[i] + sum_k t[nbr[i][k]]
//
// Sliced gather v5 = r6's lockstep skeleton with r6's two measured failure
// causes fixed:
//  (a) NS=16 (1.6 MB slices): r1/r4 measured 92-93 MB FETCH at this size;
//      r6's 3.2 MB slices measured 177 MB (drift: 2 slices > 4 MiB L2).
//  (b) IN-WINDOW clamp: when a chunk's slice-run is done, the wasted
//      lockstep load targets row s*SLICE_ROWS (first row of the CURRENT
//      slice -- one permanently hot line, L1/L2 hit) instead of r6's
//      ssort slot 16 = a random LAST-slice row that polluted every
//      earlier slice window. LDS slot read stays in-bounds via min(j,16);
//      accumulate stays predicated (clamp row is real data, not zeros).
// PASS SIGNATURE: FETCH ~95-110 MB AND gather < 62 us (r0 flat level).
__launch_bounds__(256, 4)
__global__ void gather_sum_kernel(const unsigned short* __restrict__ T,
                                  const int* __restrict__ nbr,
                                  float* __restrict__ out) {
    __shared__ int ssort[EDGES_PER_BLK * 17];   // slice-sorted indices (5.4 KB)
    __shared__ int soff[EDGES_PER_BLK * 17];    // per-edge slice prefix, NS+1 (5.4 KB)
    __shared__ int scur[EDGES_PER_BLK * 17];    // counters/cursors (5.4 KB)

    const int tid   = threadIdx.x;
    const int edge0 = blockIdx.x * EDGES_PER_BLK;
    const int el    = tid >> 4;        // 0..15 edge-in-chunk
    const int lane  = tid & 15;        // feature group: feats lane*8..+8

    // ---- per-edge counting sort by slice (threads 0..79, one per edge) ----
    if (tid < EDGES_PER_BLK) {
        const int t = tid;
        const unsigned self = (unsigned)(edge0 + t);          // always < E_EDGES
        const int* np = nbr + (size_t)(edge0 + t) * KNB;

        unsigned idxs[KNB];
        #pragma unroll
        for (int k = 0; k < KNB; k += 4) {
            uint4 q = *(const uint4*)(np + k);
            idxs[k] = q.x; idxs[k + 1] = q.y; idxs[k + 2] = q.z; idxs[k + 3] = q.w;
        }

        #pragma unroll
        for (int s = 0; s < NS; ++s) scur[t * 17 + s] = 0;
        #pragma unroll
        for (int k = 0; k < KNB; ++k)
            scur[t * 17 + idxs[k] / SLICE_ROWS] += 1;
        scur[t * 17 + self / SLICE_ROWS] += 1;

        int run = 0;
        #pragma unroll
        for (int s = 0; s < NS; ++s) {
            int c0 = scur[t * 17 + s];
            soff[t * 17 + s] = run;
            scur[t * 17 + s] = run;     // becomes scatter cursor
            run += c0;
        }
        soff[t * 17 + NS] = run;        // == 17

        #pragma unroll
        for (int k = 0; k < KNB; ++k) {
            int s = (int)(idxs[k] / SLICE_ROWS);
            ssort[t * 17 + scur[t * 17 + s]++] = (int)idxs[k];
        }
        {
            int s = (int)(self / SLICE_ROWS);
            ssort[t * 17 + scur[t * 17 + s]++] = (int)self;
        }
    }
    __syncthreads();

    const unsigned short* Tb = T + (size_t)lane * 8;

    // ---- named per-chunk state (spill-proof: no arrays) ----
    // ssort and soff now share stride 17 -> one base per chunk.
#define DECL_CHUNK(c) \
    f32x4 accL##c = {0.f, 0.f, 0.f, 0.f}; \
    f32x4 accH##c = {0.f, 0.f, 0.f, 0.f}; \
    int   j##c = 0; \
    const int b##c = (c * 16 + el) * 17;

    DECL_CHUNK(0) DECL_CHUNK(1) DECL_CHUNK(2) DECL_CHUNK(3) DECL_CHUNK(4)
#undef DECL_CHUNK

    for (int s = 0; s < NS; ++s) {
        // Slice bounds for all 5 chunks (LDS, issued together).
        const int e0 = soff[b0 + s + 1];
        const int e1 = soff[b1 + s + 1];
        const int e2 = soff[b2 + s + 1];
        const int e3 = soff[b3 + s + 1];
        const int e4 = soff[b4 + s + 1];
        const int zrow = s * SLICE_ROWS;   // in-window clamp row (hot line)

        while (true) {
            const bool p0 = j0 < e0, p1 = j1 < e1, p2 = j2 < e2,
                       p3 = j3 < e3, p4 = j4 < e4;
            if (!__any((int)(p0 | p1 | p2 | p3 | p4))) break;

            // 1. index reads (LDS slot in-bounds via min; override with the
            //    in-window clamp row when this chunk's run is done)
            int i0 = ssort[b0 + (j0 < 17 ? j0 : 16)]; i0 = p0 ? i0 : zrow;
            int i1 = ssort[b1 + (j1 < 17 ? j1 : 16)]; i1 = p1 ? i1 : zrow;
            int i2 = ssort[b2 + (j2 < 17 ? j2 : 16)]; i2 = p2 ? i2 : zrow;
            int i3 = ssort[b3 + (j3 < 17 ? j3 : 16)]; i3 = p3 ? i3 : zrow;
            int i4 = ssort[b4 + (j4 < 17 ? j4 : 16)]; i4 = p4 ? i4 : zrow;

            // 2. unconditional loads — all 5 in flight before any use
            const uint4 v0 = *(const uint4*)(Tb + (size_t)i0 * HID);
            const uint4 v1 = *(const uint4*)(Tb + (size_t)i1 * HID);
            const uint4 v2 = *(const uint4*)(Tb + (size_t)i2 * HID);
            const uint4 v3 = *(const uint4*)(Tb + (size_t)i3 * HID);
            const uint4 v4 = *(const uint4*)(Tb + (size_t)i4 * HID);
            __builtin_amdgcn_sched_barrier(0);   // pin the load group above uses

            // 3. branchless predicated accumulate (+0.0 no-op when masked)
#define ACC_CHUNK(c) { \
            uint4 w_; \
            w_.x = p##c ? v##c.x : 0u; \
            w_.y = p##c ? v##c.y : 0u; \
            w_.z = p##c ? v##c.z : 0u; \
            w_.w = p##c ? v##c.w : 0u; \
            accL##c += declo(w_); \
            accH##c += dechi(w_); \
            j##c += (int)p##c; }

            ACC_CHUNK(0) ACC_CHUNK(1) ACC_CHUNK(2) ACC_CHUNK(3) ACC_CHUNK(4)
#undef ACC_CHUNK
        }
    }

    // Final store: nontemporal f32x4 so the 50 MB out-stream doesn't evict
    // the L2 slice window.
#define STORE_CHUNK(c) { \
    const int edge_ = edge0 + c * 16 + el; \
    float* op_ = out + (size_t)edge_ * HID + lane * 8; \
    __builtin_nontemporal_store(accL##c, (f32x4*)op_); \
    __builtin_nontemporal_store(accH##c, (f32x4*)(op_ + 4)); \
    }

    STORE_CHUNK(0) STORE_CHUNK(1) STORE_CHUNK(2) STORE_CHUNK(3) STORE_CHUNK(4)
#undef STORE_CHUNK
}

extern "C" void kernel_launch(void* const* d_in, const int* in_sizes, int n_in,
                              void* d_out, int out_size, void* d_ws, size_t ws_size,
                              hipStream_t stream) {
    const float* edge_feats = (const float*)d_in[0];   // [E, 256] fp32
    const int*   neighbors  = (const int*)d_in[1];     // [E, 16] int32
    const float* W          = (const float*)d_in[2];   // [256, 128] fp32
    const float* b          = (const float*)d_in[3];   // [128] fp32
    float*       out        = (float*)d_out;           // [E, 128] fp32

    unsigned short* Wtf = (unsigned short*)d_ws;                      // 64 KB, fragment order
    unsigned short* T   = (unsigned short*)d_ws + (size_t)IN_F * HID; // 25.6 MB

    conv_w_kernel<<<16, 256, 0, stream>>>(W, Wtf);
    gemm_t_kernel<<<GEMM_GRID, 256, 0, stream>>>(edge_feats, Wtf, b, T);
    gather_sum_kernel<<<GATHER_GRID, 256, 0, stream>>>(T, neighbors, out);
}

// Round 8
// 234.123 us; speedup vs baseline: 1.0796x; 1.0796x over previous
//
#include <hip/hip_runtime.h>
#include <hip/hip_bf16.h>
#include <stdint.h>

#define E_EDGES 100000
#define IN_F    256
#define HID     128
#define KNB     16
#define NCHUNK  ((E_EDGES + 63) / 64)   // 1563
#define GEMM_GRID 512

// ---- sliced gather parameters ----
// NS=8 (3.2 MB slices): lockstep waste = E[max of 5 runs] ~ 1.8x (NS=16 is
// 2.2x and its VALU floor alone exceeds r0's total). Locality relies on FULL
// co-residency (5 blk/CU, 1250 blocks): r4 (5/CU) fetched 92 MB; r6/r7
// (4/CU, 226 late blocks) fetched 155-177 MB.
#define NS          8
#define SLICE_ROWS  12500
#define GCHUNKS     5                    // 5 chunks x 16 edges = 80 edges/block
#define EDGES_PER_BLK (GCHUNKS * 16)     // 80
#define GATHER_GRID (E_EDGES / EDGES_PER_BLK)   // 1250, exact
#define ZROW        E_EDGES              // zeroed T row: waste-load target

typedef short bf16x8 __attribute__((ext_vector_type(8)));
typedef float f32x4  __attribute__((ext_vector_type(4)));

__device__ __forceinline__ unsigned short f2bf(float f) {
    union { float f; unsigned u; } v; v.f = f;
    unsigned u = v.u;
    u += 0x7fffu + ((u >> 16) & 1u);   // round-to-nearest-even
    return (unsigned short)(u >> 16);
}

// W [256][128] fp32 -> Wtf: bf16 in MFMA B-fragment order.
// Also zeroes T row ZROW (the gather's waste-load target).
__global__ void conv_w_kernel(const float* __restrict__ W, unsigned short* __restrict__ Wtf,
                              unsigned short* __restrict__ T) {
    if (blockIdx.x == 0 && threadIdx.x < 16) {
        uint4 z = {0u, 0u, 0u, 0u};
        ((uint4*)(T + (size_t)ZROW * HID))[threadIdx.x] = z;
    }
    int d = blockIdx.x * 256 + threadIdx.x;   // 0..4095
    int f = d >> 6, L = d & 63;
    int k0 = f >> 3, ct = f & 7, quad = L >> 4, l15 = L & 15;
    int n  = ct * 16 + l15;
    int kb = (k0 * 4 + quad) * 8;
    const float* wp = W + (size_t)kb * HID + n;
    unsigned short h[8];
    #pragma unroll
    for (int j = 0; j < 8; ++j) h[j] = f2bf(wp[(size_t)j * HID]);
    uint4 o;
    o.x = (unsigned)h[0] | ((unsigned)h[1] << 16);
    o.y = (unsigned)h[2] | ((unsigned)h[3] << 16);
    o.z = (unsigned)h[4] | ((unsigned)h[5] << 16);
    o.w = (unsigned)h[6] | ((unsigned)h[7] << 16);
    *(uint4*)(Wtf + (size_t)d * 8) = o;
}

// T = A @ W + b (A fp32, converted in-reg), stored bf16 [E][128]. (unchanged)
__launch_bounds__(256, 2)
__global__ void gemm_t_kernel(const float* __restrict__ A,
                              const unsigned short* __restrict__ Wtf,
                              const float* __restrict__ bias,
                              unsigned short* __restrict__ T) {
    __shared__ unsigned short Bs[32768];   // 64 KB, fragment order
    const int tid  = threadIdx.x;
    const int wave = tid >> 6;
    const int lane = tid & 63;
    const int l15  = lane & 15;
    const int quad = lane >> 4;

    int c = blockIdx.x;
    int arow = c * 64 + wave * 16 + l15;
    if (arow >= E_EDGES) arow = E_EDGES - 1;
    const float* ap = A + (size_t)arow * IN_F + quad * 8;
    float4 af32[16];
    #pragma unroll
    for (int k0 = 0; k0 < 8; ++k0) {
        af32[2 * k0]     = *(const float4*)(ap + k0 * 32);
        af32[2 * k0 + 1] = *(const float4*)(ap + k0 * 32 + 4);
    }

    #pragma unroll
    for (int it = 0; it < 16; ++it) {
        int d = it * 256 + tid;
        *(uint4*)(Bs + (size_t)d * 8) = *(const uint4*)(Wtf + (size_t)d * 8);
    }

    float4 bv4[8];
    #pragma unroll
    for (int ct = 0; ct < 8; ++ct)
        bv4[ct] = *(const float4*)(bias + ct * 16 + quad * 4);

    __syncthreads();

    for (; c < NCHUNK; c += GEMM_GRID) {
        bf16x8 apre[8];
        #pragma unroll
        for (int k0 = 0; k0 < 8; ++k0) {
            float4 lo = af32[2 * k0], hi = af32[2 * k0 + 1];
            bf16x8 f;
            f[0] = (short)f2bf(lo.x); f[1] = (short)f2bf(lo.y);
            f[2] = (short)f2bf(lo.z); f[3] = (short)f2bf(lo.w);
            f[4] = (short)f2bf(hi.x); f[5] = (short)f2bf(hi.y);
            f[6] = (short)f2bf(hi.z); f[7] = (short)f2bf(hi.w);
            apre[k0] = f;
        }

        {
            int cn = c + GEMM_GRID;
            int arow2 = cn * 64 + wave * 16 + l15;
            if (arow2 >= E_EDGES) arow2 = E_EDGES - 1;
            const float* ap2 = A + (size_t)arow2 * IN_F + quad * 8;
            #pragma unroll
            for (int k0 = 0; k0 < 8; ++k0) {
                af32[2 * k0]     = *(const float4*)(ap2 + k0 * 32);
                af32[2 * k0 + 1] = *(const float4*)(ap2 + k0 * 32 + 4);
            }
        }
        __builtin_amdgcn_sched_barrier(0);

        f32x4 acc[8] = {};
        #pragma unroll
        for (int k0 = 0; k0 < 8; ++k0) {
            #pragma unroll
            for (int ct = 0; ct < 8; ++ct) {
                bf16x8 bf = *(const bf16x8*)(Bs + ((size_t)((k0 * 8 + ct) * 64 + lane)) * 8);
                acc[ct] = __builtin_amdgcn_mfma_f32_16x16x32_bf16(bf, apre[k0], acc[ct], 0, 0, 0);
            }
        }

        const int row = c * 64 + wave * 16 + l15;
        if (row < E_EDGES) {
            unsigned short* tp = T + (size_t)row * HID + quad * 4;
            #pragma unroll
            for (int ct = 0; ct < 8; ++ct) {
                unsigned short h0 = f2bf(acc[ct][0] + bv4[ct].x);
                unsigned short h1 = f2bf(acc[ct][1] + bv4[ct].y);
                unsigned short h2 = f2bf(acc[ct][2] + bv4[ct].z);
                unsigned short h3 = f2bf(acc[ct][3] + bv4[ct].w);
                uint2 o;
                o.x = (unsigned)h0 | ((unsigned)h1 << 16);
                o.y = (unsigned)h2 | ((unsigned)h3 << 16);
                *(uint2*)(tp + ct * 16) = o;
            }
        }
    }
}

// bf16x8 (as uint4) -> two f32x4, BY VALUE (SROA-safe).
__device__ __forceinline__ float u2f(unsigned u) {
    union { unsigned u; float f; } c; c.u = u; return c.f;
}
__device__ __forceinline__ f32x4 declo(uint4 v) {
    f32x4 r = { u2f(v.x << 16), u2f(v.x & 0xffff0000u),
                u2f(v.y << 16), u2f(v.y & 0xffff0000u) };
    return r;
}
__device__ __forceinline__ f32x4 dechi(uint4 v) {
    f32x4 r = { u2f(v.z << 16), u2f(v.z & 0xffff0000u),
                u2f(v.w << 16), u2f(v.w & 0xffff0000u) };
    return r;
}

// out[i] = t[i] + sum_k t[nbr[i][k]]
//
// Sliced gather v6 = lockstep NS=8 with the three measured leaks fixed:
//  (a) FULL co-residency: launch_bounds(256,5) -> all 1250 blocks resident
//      (r6/r7 ran 4/CU: 226 late blocks re-missed every slice, +60 MB fetch;
//      r4 at 5/CU measured 92 MB).
//  (b) ZERO-ROW waste loads: done-chunks load T[ZROW] (zeroed by conv_w) and
//      accumulate UNCONDITIONALLY -- deletes 4 cndmask/chunk/round (~25% of
//      round VALU) and the target line is permanently L2-hot everywhere
//      (in no slice's way, unlike r6's last-slice clamp row).
//  (c) NS=8 keeps lockstep round waste at 1.8x (NS=16's 2.2x puts the VALU
//      floor alone above r0's 62 us total).
// PASS SIGNATURE: FETCH ~105-130 MB AND gather < 62 us; else slicing is
// abandoned next round (revert to r0 flat gather).
__launch_bounds__(256, 5)
__global__ void gather_sum_kernel(const unsigned short* __restrict__ T,
                                  const int* __restrict__ nbr,
                                  float* __restrict__ out) {
    __shared__ int ssort[EDGES_PER_BLK * 17];   // slice-sorted indices (5.4 KB)
    __shared__ int soff[EDGES_PER_BLK * 9];     // per-edge slice prefix (2.9 KB)
    __shared__ int scur[EDGES_PER_BLK * 9];     // counters/cursors (2.9 KB)

    const int tid   = threadIdx.x;
    const int edge0 = blockIdx.x * EDGES_PER_BLK;
    const int el    = tid >> 4;        // 0..15 edge-in-chunk
    const int lane  = tid & 15;        // feature group: feats lane*8..+8

    // ---- per-edge counting sort by slice (threads 0..79, one per edge) ----
    if (tid < EDGES_PER_BLK) {
        const int t = tid;
        const unsigned self = (unsigned)(edge0 + t);          // always < E_EDGES
        const int* np = nbr + (size_t)(edge0 + t) * KNB;

        unsigned idxs[KNB];
        #pragma unroll
        for (int k = 0; k < KNB; k += 4) {
            uint4 q = *(const uint4*)(np + k);
            idxs[k] = q.x; idxs[k + 1] = q.y; idxs[k + 2] = q.z; idxs[k + 3] = q.w;
        }

        #pragma unroll
        for (int s = 0; s < NS; ++s) scur[t * 9 + s] = 0;
        #pragma unroll
        for (int k = 0; k < KNB; ++k)
            scur[t * 9 + idxs[k] / SLICE_ROWS] += 1;
        scur[t * 9 + self / SLICE_ROWS] += 1;

        int run = 0;
        #pragma unroll
        for (int s = 0; s < NS; ++s) {
            int c0 = scur[t * 9 + s];
            soff[t * 9 + s] = run;
            scur[t * 9 + s] = run;     // becomes scatter cursor
            run += c0;
        }
        soff[t * 9 + NS] = run;        // == 17

        #pragma unroll
        for (int k = 0; k < KNB; ++k) {
            int s = (int)(idxs[k] / SLICE_ROWS);
            ssort[t * 17 + scur[t * 9 + s]++] = (int)idxs[k];
        }
        {
            int s = (int)(self / SLICE_ROWS);
            ssort[t * 17 + scur[t * 9 + s]++] = (int)self;
        }
    }
    __syncthreads();

    const unsigned short* Tb = T + (size_t)lane * 8;

    // ---- named per-chunk state (spill-proof: no arrays) ----
#define DECL_CHUNK(c) \
    f32x4 accL##c = {0.f, 0.f, 0.f, 0.f}; \
    f32x4 accH##c = {0.f, 0.f, 0.f, 0.f}; \
    int   j##c = 0; \
    const int sb##c = (c * 16 + el) * 17; \
    const int ob##c = (c * 16 + el) * 9;

    DECL_CHUNK(0) DECL_CHUNK(1) DECL_CHUNK(2) DECL_CHUNK(3) DECL_CHUNK(4)
#undef DECL_CHUNK

    for (int s = 0; s < NS; ++s) {
        const int e0 = soff[ob0 + s + 1];
        const int e1 = soff[ob1 + s + 1];
        const int e2 = soff[ob2 + s + 1];
        const int e3 = soff[ob3 + s + 1];
        const int e4 = soff[ob4 + s + 1];

        while (true) {
            const bool p0 = j0 < e0, p1 = j1 < e1, p2 = j2 < e2,
                       p3 = j3 < e3, p4 = j4 < e4;
            if (!__any((int)(p0 | p1 | p2 | p3 | p4))) break;

            // 1. index reads (LDS slot bounds-clamped; done-chunks target the
            //    zeroed row ZROW -> unconditional accumulate is a no-op)
            int i0 = ssort[sb0 + (j0 < 17 ? j0 : 16)]; i0 = p0 ? i0 : ZROW;
            int i1 = ssort[sb1 + (j1 < 17 ? j1 : 16)]; i1 = p1 ? i1 : ZROW;
            int i2 = ssort[sb2 + (j2 < 17 ? j2 : 16)]; i2 = p2 ? i2 : ZROW;
            int i3 = ssort[sb3 + (j3 < 17 ? j3 : 16)]; i3 = p3 ? i3 : ZROW;
            int i4 = ssort[sb4 + (j4 < 17 ? j4 : 16)]; i4 = p4 ? i4 : ZROW;

            // 2. unconditional loads — all 5 in flight before any use
            const uint4 v0 = *(const uint4*)(Tb + (size_t)i0 * HID);
            const uint4 v1 = *(const uint4*)(Tb + (size_t)i1 * HID);
            const uint4 v2 = *(const uint4*)(Tb + (size_t)i2 * HID);
            const uint4 v3 = *(const uint4*)(Tb + (size_t)i3 * HID);
            const uint4 v4 = *(const uint4*)(Tb + (size_t)i4 * HID);
            __builtin_amdgcn_sched_barrier(0);   // pin the load group above uses

            // 3. unconditional accumulate (ZROW loads add 0.0)
#define ACC_CHUNK(c) { \
            accL##c += declo(v##c); \
            accH##c += dechi(v##c); \
            j##c += (int)p##c; }

            ACC_CHUNK(0) ACC_CHUNK(1) ACC_CHUNK(2) ACC_CHUNK(3) ACC_CHUNK(4)
#undef ACC_CHUNK
        }
    }

    // Final store: nontemporal f32x4 so the 50 MB out-stream doesn't evict
    // the L2 slice window.
#define STORE_CHUNK(c) { \
    const int edge_ = edge0 + c * 16 + el; \
    float* op_ = out + (size_t)edge_ * HID + lane * 8; \
    __builtin_nontemporal_store(accL##c, (f32x4*)op_); \
    __builtin_nontemporal_store(accH##c, (f32x4*)(op_ + 4)); \
    }

    STORE_CHUNK(0) STORE_CHUNK(1) STORE_CHUNK(2) STORE_CHUNK(3) STORE_CHUNK(4)
#undef STORE_CHUNK
}

extern "C" void kernel_launch(void* const* d_in, const int* in_sizes, int n_in,
                              void* d_out, int out_size, void* d_ws, size_t ws_size,
                              hipStream_t stream) {
    const float* edge_feats = (const float*)d_in[0];   // [E, 256] fp32
    const int*   neighbors  = (const int*)d_in[1];     // [E, 16] int32
    const float* W          = (const float*)d_in[2];   // [256, 128] fp32
    const float* b          = (const float*)d_in[3];   // [128] fp32
    float*       out        = (float*)d_out;           // [E, 128] fp32

    unsigned short* Wtf = (unsigned short*)d_ws;                      // 64 KB, fragment order
    unsigned short* T   = (unsigned short*)d_ws + (size_t)IN_F * HID; // 25.6 MB (+1 zero row)

    conv_w_kernel<<<16, 256, 0, stream>>>(W, Wtf, T);
    gemm_t_kernel<<<GEMM_GRID, 256, 0, stream>>>(edge_feats, Wtf, b, T);
    gather_sum_kernel<<<GATHER_GRID, 256, 0, stream>>>(T, neighbors, out);
}